// Round 15
// baseline (332.998 us; speedup 1.0000x reference)
//
#include <hip/hip_runtime.h>
#include <stdint.h>

#define B_ 1024
#define D_ 784
#define H_ 1024
#define BH_ (B_ * H_)
#define LOG2E 1.4426950408889634f

// Segments: {0,144,272,400,528,656,784} (all %16); G ranges: first 5 spans.
// VWb: per (step i, hb) a 1KB image of 512 ushorts: [0,256) = V bf16, [256,512) = W*log2e bf16.
// ws: VWb [788][4][512] ushort 3.23 MB | G [5][B][H] fp32 21 MB

__device__ __forceinline__ unsigned short bf16_rne(float x) {
    unsigned b = __float_as_uint(x);
    return (unsigned short)((b + 0x7FFFu + ((b >> 16) & 1u)) >> 16);
}

__device__ __forceinline__ int seg_bound(int s) {
    const int b[7] = {0, 144, 272, 400, 528, 656, 784};
    return b[s];
}

// ---------- fat prep ----------
// blocks [0,800): build VWb; blocks [800,2080): G partial GEMMs (K=16, all-thread loads)
__global__ __launch_bounds__(256) void prep(const float* __restrict__ V,
                                            const float* __restrict__ W,
                                            const float* __restrict__ px,
                                            unsigned short* __restrict__ VWb,
                                            float* __restrict__ G) {
    __shared__ float smem[2048];
    const int t = threadIdx.x;

    if (blockIdx.x < 800) {
        int i0 = (blockIdx.x % 25) * 32;
        int h0 = (blockIdx.x / 25) * 32;
        int tx = t & 31, ty = t >> 5;   // 32 x 8
        int hb = h0 >> 8, hr = h0 & 255;
#pragma unroll
        for (int j = 0; j < 4; ++j) {
            int i = i0 + ty + j * 8;
            if (i < D_)
                VWb[((size_t)i * 4 + hb) * 512 + hr + tx] = bf16_rne(V[(size_t)i * H_ + h0 + tx]);
        }
#pragma unroll
        for (int j = 0; j < 4; ++j) {
            int h = h0 + ty + j * 8;
            int i = i0 + tx;
            float v = 0.f;
            if (i < D_) v = W[(size_t)h * D_ + i] * LOG2E;
            smem[(ty + j * 8) * 33 + tx] = v;
        }
        __syncthreads();
#pragma unroll
        for (int j = 0; j < 4; ++j) {
            int i = i0 + ty + j * 8;
            if (i < D_)
                VWb[((size_t)i * 4 + hb) * 512 + 256 + hr + tx] = bf16_rne(smem[tx * 33 + ty + j * 8]);
        }
    } else {
        float* xs = smem;           // [16][64]
        float* ws = smem + 1024;    // [16][64]
        int idx = blockIdx.x - 800;
        int r   = idx >> 8;                       // 0..4
        int b0  = (idx & 15) * 64;
        int h0  = ((idx >> 4) & 15) * 64;
        int j0s = seg_bound(r), j1s = seg_bound(r + 1);

        const int tb = t >> 4, th = t & 15;       // 16x16, each 4b x 4h
        const int bq = t >> 2;                    // 0..63
        const int jq = (t & 3) * 4;               // 0,4,8,12
        float acc[4][4];
#pragma unroll
        for (int bi = 0; bi < 4; ++bi)
#pragma unroll
            for (int hh = 0; hh < 4; ++hh) acc[bi][hh] = 0.f;

        for (int j0 = j0s; j0 < j1s; j0 += 16) {  // range lengths all %16 == 0
            float4 xv = *(const float4*)(px + (size_t)(b0 + bq) * D_ + j0 + jq);
            float4 wv = *(const float4*)(W  + (size_t)(h0 + bq) * D_ + j0 + jq);
            __syncthreads();
            xs[(jq + 0) * 64 + bq] = xv.x;
            xs[(jq + 1) * 64 + bq] = xv.y;
            xs[(jq + 2) * 64 + bq] = xv.z;
            xs[(jq + 3) * 64 + bq] = xv.w;
            ws[(jq + 0) * 64 + bq] = wv.x * LOG2E;
            ws[(jq + 1) * 64 + bq] = wv.y * LOG2E;
            ws[(jq + 2) * 64 + bq] = wv.z * LOG2E;
            ws[(jq + 3) * 64 + bq] = wv.w * LOG2E;
            __syncthreads();
#pragma unroll
            for (int jj = 0; jj < 16; ++jj) {
                float4 xq = *(float4*)&xs[jj * 64 + tb * 4];
                float4 wq = *(float4*)&ws[jj * 64 + th * 4];
                float xa[4] = {xq.x, xq.y, xq.z, xq.w};
                float wa[4] = {wq.x, wq.y, wq.z, wq.w};
#pragma unroll
                for (int bi = 0; bi < 4; ++bi)
#pragma unroll
                    for (int hh = 0; hh < 4; ++hh)
                        acc[bi][hh] = fmaf(xa[bi], wa[hh], acc[bi][hh]);
            }
        }
        float* dst = G + (size_t)r * BH_;
#pragma unroll
        for (int bi = 0; bi < 4; ++bi) {
            float4 o = make_float4(acc[bi][0], acc[bi][1], acc[bi][2], acc[bi][3]);
            *(float4*)(dst + (size_t)(b0 + tb * 4 + bi) * H_ + h0 + th * 4) = o;
        }
    }
}

// ---------- DPP reduce: both 32-lane halves simultaneously ----------
template <int CTRL>
__device__ __forceinline__ float dpp_add(float p) {
    int s = __builtin_amdgcn_update_dpp(0, __float_as_int(p), CTRL, 0xf, 0xf, true);
    return p + __int_as_float(s);
}
__device__ __forceinline__ float reduce_halves(float p) {
    p = dpp_add<0x111>(p);
    p = dpp_add<0x112>(p);
    p = dpp_add<0x114>(p);
    p = dpp_add<0x118>(p);
    p = dpp_add<0x142>(p);   // lane31 = sum(0..31), lane63 = sum(32..63)
    return p;
}

// 8 packed bf16 (uint4) -> 8 floats; high elements keep junk low-mantissa bits
__device__ __forceinline__ void cvt8(uint4 u, float4& a, float4& b) {
    a.x = __uint_as_float(u.x << 16);
    a.y = __uint_as_float(u.x);
    a.z = __uint_as_float(u.y << 16);
    a.w = __uint_as_float(u.y);
    b.x = __uint_as_float(u.z << 16);
    b.y = __uint_as_float(u.z);
    b.z = __uint_as_float(u.w << 16);
    b.w = __uint_as_float(u.w);
}

// ---------- main scan: identical to R14 except seg_bound table ----------
__global__ __launch_bounds__(256, 8) void nade_main(
    const float* __restrict__ px,            // [B, D]
    const float* __restrict__ c,             // [H]
    const unsigned short* __restrict__ VWb,  // bf16 images
    const float* __restrict__ G,             // [5][B][H] (log2 domain)
    const float* __restrict__ bias,          // [D]
    float* __restrict__ out)                 // [B, D] — written directly
{
    __shared__ float4 red[2][4][2];          // [parity][wid][half] — 256 B

    const int lane = threadIdx.x & 63;
    const int wid  = threadIdx.x >> 6;       // = hb
    const int bid  = blockIdx.x;             // 0..3071
    const int s    = bid % 6;
    const int rp   = bid / 6;                // 0..511
    const int half = lane >> 5;
    const int row  = rp * 2 + half;
    const int hl   = lane & 31;
    const int h0   = wid * 256 + hl * 8;

    const int i0s = seg_bound(s), i1s = seg_bound(s + 1);

    // A (log2 domain) = c*log2e + sum_{r<s} G_r
    float A[8];
    {
        float4 c0 = *(const float4*)(c + h0);
        float4 c1 = *(const float4*)(c + h0 + 4);
        A[0] = c0.x * LOG2E; A[1] = c0.y * LOG2E; A[2] = c0.z * LOG2E; A[3] = c0.w * LOG2E;
        A[4] = c1.x * LOG2E; A[5] = c1.y * LOG2E; A[6] = c1.z * LOG2E; A[7] = c1.w * LOG2E;
        for (int r = 0; r < s; ++r) {
            const float* gp = G + (size_t)r * BH_ + (size_t)row * H_ + h0;
            float4 g0 = *(const float4*)(gp);
            float4 g1 = *(const float4*)(gp + 4);
            A[0] += g0.x; A[1] += g0.y; A[2] += g0.z; A[3] += g0.w;
            A[4] += g1.x; A[5] += g1.y; A[6] += g1.z; A[7] += g1.w;
        }
    }

    const float* xp = px + (size_t)row * D_;
    const uint4* vw = (const uint4*)VWb + ((size_t)i0s * 4 + wid) * 64 + hl;

    // one step (8 h): hw exp2, grouped rcp over 8 q's; clamp exp arg to 15
    auto step8 = [&A](const float4& v0, const float4& v1,
                      const float4& w0, const float4& w1, float xi) -> float {
        float va[8] = {v0.x, v0.y, v0.z, v0.w, v1.x, v1.y, v1.z, v1.w};
        float wa[8] = {w0.x, w0.y, w0.z, w0.w, w1.x, w1.y, w1.z, w1.w};
        float q[8];
#pragma unroll
        for (int k = 0; k < 8; ++k) {
            float e = __builtin_amdgcn_exp2f(fminf(15.f, -A[k]));
            q[k] = 1.f + e;
            A[k] = fmaf(wa[k], xi, A[k]);
        }
        float a01 = fmaf(va[0], q[1], va[1] * q[0]);
        float a23 = fmaf(va[2], q[3], va[3] * q[2]);
        float a45 = fmaf(va[4], q[5], va[5] * q[4]);
        float a67 = fmaf(va[6], q[7], va[7] * q[6]);
        float q01 = q[0] * q[1], q23 = q[2] * q[3];
        float q45 = q[4] * q[5], q67 = q[6] * q[7];
        float n0123 = fmaf(a01, q23, a23 * q01);
        float n4567 = fmaf(a45, q67, a67 * q45);
        float q0123 = q01 * q23, q4567 = q45 * q67;
        float r = __builtin_amdgcn_rcpf(q0123 * q4567);
        float n = fmaf(n0123, q4567, n4567 * q0123);
        return n * r;
    };

    // preload current raw quads + first x group
    uint4 uv = vw[0], uw = vw[32];
    vw += 256;
    float4 xq = *(const float4*)(xp + i0s);

    for (int ib = i0s; ib < i1s; ib += 4) {     // all segment lengths %4 == 0
        int xb = (ib + 4 < i1s) ? (ib + 4) : i0s;
        float4 xq_n = *(const float4*)(xp + xb);
        float xa[4] = {xq.x, xq.y, xq.z, xq.w};
        float pr[4];
#pragma unroll
        for (int j = 0; j < 4; ++j) {
            uint4 uvn = vw[0], uwn = vw[32];    // prefetch next step (images padded past 784)
            vw += 256;
            float4 v0, v1, w0, w1;
            cvt8(uv, v0, v1);
            cvt8(uw, w0, w1);
            float p = step8(v0, v1, w0, w1, xa[j]);
            pr[j] = reduce_halves(p);
            uv = uvn; uw = uwn;
        }
        const int par = (ib >> 2) & 1;
        if (hl == 31) red[par][wid][half] = make_float4(pr[0], pr[1], pr[2], pr[3]);
        __syncthreads();
        if (threadIdx.x < 2) {                  // thread t handles row rp*2+t
            float4 b4 = *(const float4*)(bias + ib);
            float4 p0 = red[par][0][threadIdx.x];
            float4 p1 = red[par][1][threadIdx.x];
            float4 p2 = red[par][2][threadIdx.x];
            float4 p3 = red[par][3][threadIdx.x];
            float4 o;
            o.x = b4.x + ((p0.x + p1.x) + (p2.x + p3.x));
            o.y = b4.y + ((p0.y + p1.y) + (p2.y + p3.y));
            o.z = b4.z + ((p0.z + p1.z) + (p2.z + p3.z));
            o.w = b4.w + ((p0.w + p1.w) + (p2.w + p3.w));
            *(float4*)(out + (size_t)(rp * 2 + threadIdx.x) * D_ + ib) = o;
        }
        xq = xq_n;
    }
}

extern "C" void kernel_launch(void* const* d_in, const int* in_sizes, int n_in,
                              void* d_out, int out_size, void* d_ws, size_t ws_size,
                              hipStream_t stream) {
    const float* px   = (const float*)d_in[0];  // [B, D]
    const float* W    = (const float*)d_in[1];  // [H, D]
    const float* c    = (const float*)d_in[2];  // [H]
    const float* V    = (const float*)d_in[3];  // [D, H]
    const float* bias = (const float*)d_in[4];  // [D]
    float* out = (float*)d_out;                 // [B, D]

    unsigned short* VWb = (unsigned short*)d_ws;              // 788*4*512 ushorts = 3.23 MB
    float* G    = (float*)((char*)d_ws + (size_t)788 * 4096); // [5][B][H]

    prep<<<dim3(2080), 256, 0, stream>>>(V, W, px, VWb, G);

    // 3072 blocks x 4 waves; block = (segment, row-pair), waves = 4 hb quarters
    nade_main<<<dim3(3072), 256, 0, stream>>>(px, c, VWb, G, bias, out);
}

// Round 16
// 322.259 us; speedup vs baseline: 1.0333x; 1.0333x over previous
//
#include <hip/hip_runtime.h>
#include <stdint.h>

#define B_ 1024
#define D_ 784
#define H_ 1024
#define BH_ (B_ * H_)
#define LOG2E 1.4426950408889634f

// Segments: {0,136,272,400,528,656,784} (all %8); G ranges: first 5 spans.
// VWb: per (step i, hb) a 1KB image of 512 ushorts: [0,256) = V bf16, [256,512) = W*log2e bf16.
// ws: VWb [788][4][512] ushort 3.23 MB | G [5][B][H] fp32 21 MB

__device__ __forceinline__ unsigned short bf16_rne(float x) {
    unsigned b = __float_as_uint(x);
    return (unsigned short)((b + 0x7FFFu + ((b >> 16) & 1u)) >> 16);
}

__device__ __forceinline__ int seg_bound(int s) {
    const int b[7] = {0, 136, 272, 400, 528, 656, 784};
    return b[s];
}

// ---------- fat prep ----------
// blocks [0,800): build VWb; blocks [800,1440): G partial GEMMs (K=8, 128b x 64h tiles)
__global__ __launch_bounds__(256) void prep(const float* __restrict__ V,
                                            const float* __restrict__ W,
                                            const float* __restrict__ px,
                                            unsigned short* __restrict__ VWb,
                                            float* __restrict__ G) {
    __shared__ float smem[1536];
    const int t = threadIdx.x;

    if (blockIdx.x < 800) {
        int i0 = (blockIdx.x % 25) * 32;
        int h0 = (blockIdx.x / 25) * 32;
        int tx = t & 31, ty = t >> 5;   // 32 x 8
        int hb = h0 >> 8, hr = h0 & 255;
#pragma unroll
        for (int j = 0; j < 4; ++j) {
            int i = i0 + ty + j * 8;
            if (i < D_)
                VWb[((size_t)i * 4 + hb) * 512 + hr + tx] = bf16_rne(V[(size_t)i * H_ + h0 + tx]);
        }
#pragma unroll
        for (int j = 0; j < 4; ++j) {
            int h = h0 + ty + j * 8;
            int i = i0 + tx;
            float v = 0.f;
            if (i < D_) v = W[(size_t)h * D_ + i] * LOG2E;
            smem[(ty + j * 8) * 33 + tx] = v;
        }
        __syncthreads();
#pragma unroll
        for (int j = 0; j < 4; ++j) {
            int i = i0 + ty + j * 8;
            if (i < D_)
                VWb[((size_t)i * 4 + hb) * 512 + 256 + hr + tx] = bf16_rne(smem[tx * 33 + ty + j * 8]);
        }
    } else {
        float* xs = smem;           // [8][128]
        float* ws = smem + 1024;    // [8][64]
        int idx = blockIdx.x - 800;
        int r   = idx >> 7;                       // 0..4
        int b0  = (idx & 7) * 128;
        int h0  = ((idx >> 3) & 15) * 64;
        int j0s = seg_bound(r), j1s = seg_bound(r + 1);

        const int tb = t >> 4, th = t & 15;       // 16x16: each thread 8b x 4h
        float acc[8][4];
#pragma unroll
        for (int bi = 0; bi < 8; ++bi)
#pragma unroll
            for (int hh = 0; hh < 4; ++hh) acc[bi][hh] = 0.f;

        const int xr = t >> 1;                    // 0..127 (row within b tile)
        const int xj = (t & 1) * 4;               // 0 or 4

        for (int j0 = j0s; j0 < j1s; j0 += 8) {   // range lengths all %8 == 0
            float4 xv = *(const float4*)(px + (size_t)(b0 + xr) * D_ + j0 + xj);
            float4 wv = make_float4(0, 0, 0, 0);
            if (t < 128) wv = *(const float4*)(W + (size_t)(h0 + xr) * D_ + j0 + xj);
            __syncthreads();
            xs[(xj + 0) * 128 + xr] = xv.x;
            xs[(xj + 1) * 128 + xr] = xv.y;
            xs[(xj + 2) * 128 + xr] = xv.z;
            xs[(xj + 3) * 128 + xr] = xv.w;
            if (t < 128) {
                ws[(xj + 0) * 64 + xr] = wv.x * LOG2E;
                ws[(xj + 1) * 64 + xr] = wv.y * LOG2E;
                ws[(xj + 2) * 64 + xr] = wv.z * LOG2E;
                ws[(xj + 3) * 64 + xr] = wv.w * LOG2E;
            }
            __syncthreads();
#pragma unroll
            for (int jj = 0; jj < 8; ++jj) {
                float4 xq0 = *(float4*)&xs[jj * 128 + tb * 8];
                float4 xq1 = *(float4*)&xs[jj * 128 + tb * 8 + 4];
                float4 wq  = *(float4*)&ws[jj * 64 + th * 4];
                float xa[8] = {xq0.x, xq0.y, xq0.z, xq0.w, xq1.x, xq1.y, xq1.z, xq1.w};
                float wa[4] = {wq.x, wq.y, wq.z, wq.w};
#pragma unroll
                for (int bi = 0; bi < 8; ++bi)
#pragma unroll
                    for (int hh = 0; hh < 4; ++hh)
                        acc[bi][hh] = fmaf(xa[bi], wa[hh], acc[bi][hh]);
            }
        }
        float* dst = G + (size_t)r * BH_;
#pragma unroll
        for (int bi = 0; bi < 8; ++bi) {
            float4 o = make_float4(acc[bi][0], acc[bi][1], acc[bi][2], acc[bi][3]);
            *(float4*)(dst + (size_t)(b0 + tb * 8 + bi) * H_ + h0 + th * 4) = o;
        }
    }
}

// ---------- DPP reduce: both 32-lane halves simultaneously ----------
template <int CTRL>
__device__ __forceinline__ float dpp_add(float p) {
    int s = __builtin_amdgcn_update_dpp(0, __float_as_int(p), CTRL, 0xf, 0xf, true);
    return p + __int_as_float(s);
}
__device__ __forceinline__ float reduce_halves(float p) {
    p = dpp_add<0x111>(p);
    p = dpp_add<0x112>(p);
    p = dpp_add<0x114>(p);
    p = dpp_add<0x118>(p);
    p = dpp_add<0x142>(p);   // lane31 = sum(0..31), lane63 = sum(32..63)
    return p;
}

// 8 packed bf16 (uint4) -> 8 floats; high elements keep junk low-mantissa bits
__device__ __forceinline__ void cvt8(uint4 u, float4& a, float4& b) {
    a.x = __uint_as_float(u.x << 16);
    a.y = __uint_as_float(u.x);
    a.z = __uint_as_float(u.y << 16);
    a.w = __uint_as_float(u.y);
    b.x = __uint_as_float(u.z << 16);
    b.y = __uint_as_float(u.z);
    b.z = __uint_as_float(u.w << 16);
    b.w = __uint_as_float(u.w);
}

// ---------- main scan: identical to R14 ----------
__global__ __launch_bounds__(256, 8) void nade_main(
    const float* __restrict__ px,            // [B, D]
    const float* __restrict__ c,             // [H]
    const unsigned short* __restrict__ VWb,  // bf16 images
    const float* __restrict__ G,             // [5][B][H] (log2 domain)
    const float* __restrict__ bias,          // [D]
    float* __restrict__ out)                 // [B, D] — written directly
{
    __shared__ float4 red[2][4][2];          // [parity][wid][half] — 256 B

    const int lane = threadIdx.x & 63;
    const int wid  = threadIdx.x >> 6;       // = hb
    const int bid  = blockIdx.x;             // 0..3071
    const int s    = bid % 6;
    const int rp   = bid / 6;                // 0..511
    const int half = lane >> 5;
    const int row  = rp * 2 + half;
    const int hl   = lane & 31;
    const int h0   = wid * 256 + hl * 8;

    const int i0s = seg_bound(s), i1s = seg_bound(s + 1);

    // A (log2 domain) = c*log2e + sum_{r<s} G_r
    float A[8];
    {
        float4 c0 = *(const float4*)(c + h0);
        float4 c1 = *(const float4*)(c + h0 + 4);
        A[0] = c0.x * LOG2E; A[1] = c0.y * LOG2E; A[2] = c0.z * LOG2E; A[3] = c0.w * LOG2E;
        A[4] = c1.x * LOG2E; A[5] = c1.y * LOG2E; A[6] = c1.z * LOG2E; A[7] = c1.w * LOG2E;
        for (int r = 0; r < s; ++r) {
            const float* gp = G + (size_t)r * BH_ + (size_t)row * H_ + h0;
            float4 g0 = *(const float4*)(gp);
            float4 g1 = *(const float4*)(gp + 4);
            A[0] += g0.x; A[1] += g0.y; A[2] += g0.z; A[3] += g0.w;
            A[4] += g1.x; A[5] += g1.y; A[6] += g1.z; A[7] += g1.w;
        }
    }

    const float* xp = px + (size_t)row * D_;
    const uint4* vw = (const uint4*)VWb + ((size_t)i0s * 4 + wid) * 64 + hl;

    // one step (8 h): hw exp2, grouped rcp over 8 q's; clamp exp arg to 15
    auto step8 = [&A](const float4& v0, const float4& v1,
                      const float4& w0, const float4& w1, float xi) -> float {
        float va[8] = {v0.x, v0.y, v0.z, v0.w, v1.x, v1.y, v1.z, v1.w};
        float wa[8] = {w0.x, w0.y, w0.z, w0.w, w1.x, w1.y, w1.z, w1.w};
        float q[8];
#pragma unroll
        for (int k = 0; k < 8; ++k) {
            float e = __builtin_amdgcn_exp2f(fminf(15.f, -A[k]));
            q[k] = 1.f + e;
            A[k] = fmaf(wa[k], xi, A[k]);
        }
        float a01 = fmaf(va[0], q[1], va[1] * q[0]);
        float a23 = fmaf(va[2], q[3], va[3] * q[2]);
        float a45 = fmaf(va[4], q[5], va[5] * q[4]);
        float a67 = fmaf(va[6], q[7], va[7] * q[6]);
        float q01 = q[0] * q[1], q23 = q[2] * q[3];
        float q45 = q[4] * q[5], q67 = q[6] * q[7];
        float n0123 = fmaf(a01, q23, a23 * q01);
        float n4567 = fmaf(a45, q67, a67 * q45);
        float q0123 = q01 * q23, q4567 = q45 * q67;
        float r = __builtin_amdgcn_rcpf(q0123 * q4567);
        float n = fmaf(n0123, q4567, n4567 * q0123);
        return n * r;
    };

    // preload current raw quads + first x group
    uint4 uv = vw[0], uw = vw[32];
    vw += 256;
    float4 xq = *(const float4*)(xp + i0s);

    for (int ib = i0s; ib < i1s; ib += 4) {     // all segment lengths %4 == 0
        int xb = (ib + 4 < i1s) ? (ib + 4) : i0s;
        float4 xq_n = *(const float4*)(xp + xb);
        float xa[4] = {xq.x, xq.y, xq.z, xq.w};
        float pr[4];
#pragma unroll
        for (int j = 0; j < 4; ++j) {
            uint4 uvn = vw[0], uwn = vw[32];    // prefetch next step (images padded past 784)
            vw += 256;
            float4 v0, v1, w0, w1;
            cvt8(uv, v0, v1);
            cvt8(uw, w0, w1);
            float p = step8(v0, v1, w0, w1, xa[j]);
            pr[j] = reduce_halves(p);
            uv = uvn; uw = uwn;
        }
        const int par = (ib >> 2) & 1;
        if (hl == 31) red[par][wid][half] = make_float4(pr[0], pr[1], pr[2], pr[3]);
        __syncthreads();
        if (threadIdx.x < 2) {                  // thread t handles row rp*2+t
            float4 b4 = *(const float4*)(bias + ib);
            float4 p0 = red[par][0][threadIdx.x];
            float4 p1 = red[par][1][threadIdx.x];
            float4 p2 = red[par][2][threadIdx.x];
            float4 p3 = red[par][3][threadIdx.x];
            float4 o;
            o.x = b4.x + ((p0.x + p1.x) + (p2.x + p3.x));
            o.y = b4.y + ((p0.y + p1.y) + (p2.y + p3.y));
            o.z = b4.z + ((p0.z + p1.z) + (p2.z + p3.z));
            o.w = b4.w + ((p0.w + p1.w) + (p2.w + p3.w));
            *(float4*)(out + (size_t)(rp * 2 + threadIdx.x) * D_ + ib) = o;
        }
        xq = xq_n;
    }
}

extern "C" void kernel_launch(void* const* d_in, const int* in_sizes, int n_in,
                              void* d_out, int out_size, void* d_ws, size_t ws_size,
                              hipStream_t stream) {
    const float* px   = (const float*)d_in[0];  // [B, D]
    const float* W    = (const float*)d_in[1];  // [H, D]
    const float* c    = (const float*)d_in[2];  // [H]
    const float* V    = (const float*)d_in[3];  // [D, H]
    const float* bias = (const float*)d_in[4];  // [D]
    float* out = (float*)d_out;                 // [B, D]

    unsigned short* VWb = (unsigned short*)d_ws;              // 788*4*512 ushorts = 3.23 MB
    float* G    = (float*)((char*)d_ws + (size_t)788 * 4096); // [5][B][H]

    // 800 VW-build blocks + 640 GEMM blocks (5 ranges x 8 b-tiles x 16 h-tiles)
    prep<<<dim3(1440), 256, 0, stream>>>(V, W, px, VWb, G);

    // 3072 blocks x 4 waves; block = (segment, row-pair), waves = 4 hb quarters
    nade_main<<<dim3(3072), 256, 0, stream>>>(px, c, VWb, G, bias, out);
}

// Round 17
// 310.233 us; speedup vs baseline: 1.0734x; 1.0388x over previous
//
#include <hip/hip_runtime.h>
#include <stdint.h>

#define B_ 1024
#define D_ 784
#define H_ 1024
#define BH_ (B_ * H_)
#define LOG2E 1.4426950408889634f

// Segments: {0,136,272,400,528,656,784} (all %8); G ranges: first 5 spans.
// VWb: per (step i, hb) a 1KB image of 512 ushorts: [0,256) = V bf16, [256,512) = W*log2e bf16.
// ws: VWb [788][4][512] ushort 3.23 MB | G [5][B][H] fp32 21 MB

__device__ __forceinline__ unsigned short bf16_rne(float x) {
    unsigned b = __float_as_uint(x);
    return (unsigned short)((b + 0x7FFFu + ((b >> 16) & 1u)) >> 16);
}

__device__ __forceinline__ int seg_bound(int s) {
    const int b[7] = {0, 136, 272, 400, 528, 656, 784};
    return b[s];
}

// ---------- fat prep (R14 config: K=8, 64b x 64h G-tiles — measured best) ----------
__global__ __launch_bounds__(256) void prep(const float* __restrict__ V,
                                            const float* __restrict__ W,
                                            const float* __restrict__ px,
                                            unsigned short* __restrict__ VWb,
                                            float* __restrict__ G) {
    __shared__ float smem[1056];
    const int t = threadIdx.x;

    if (blockIdx.x < 800) {
        int i0 = (blockIdx.x % 25) * 32;
        int h0 = (blockIdx.x / 25) * 32;
        int tx = t & 31, ty = t >> 5;   // 32 x 8
        int hb = h0 >> 8, hr = h0 & 255;
#pragma unroll
        for (int j = 0; j < 4; ++j) {
            int i = i0 + ty + j * 8;
            if (i < D_)
                VWb[((size_t)i * 4 + hb) * 512 + hr + tx] = bf16_rne(V[(size_t)i * H_ + h0 + tx]);
        }
#pragma unroll
        for (int j = 0; j < 4; ++j) {
            int h = h0 + ty + j * 8;
            int i = i0 + tx;
            float v = 0.f;
            if (i < D_) v = W[(size_t)h * D_ + i] * LOG2E;
            smem[(ty + j * 8) * 33 + tx] = v;
        }
        __syncthreads();
#pragma unroll
        for (int j = 0; j < 4; ++j) {
            int i = i0 + ty + j * 8;
            if (i < D_)
                VWb[((size_t)i * 4 + hb) * 512 + 256 + hr + tx] = bf16_rne(smem[tx * 33 + ty + j * 8]);
        }
    } else {
        float* xs = smem;          // [8][64]
        float* ws = smem + 512;    // [8][64]
        int idx = blockIdx.x - 800;
        int r   = idx >> 8;                       // 0..4
        int b0  = (idx & 15) * 64;
        int h0  = ((idx >> 4) & 15) * 64;
        int j0s = seg_bound(r), j1s = seg_bound(r + 1);

        const int tb = t >> 4, th = t & 15;       // 16x16, each 4b x 4h
        float acc[4][4];
#pragma unroll
        for (int bi = 0; bi < 4; ++bi)
#pragma unroll
            for (int hh = 0; hh < 4; ++hh) acc[bi][hh] = 0.f;

        const int xb = t >> 3;                    // 0..31
        const int xj = t & 7;                     // 0..7
        const int wh = t >> 1, wj = (t & 1) * 4;  // for t < 128

        for (int j0 = j0s; j0 < j1s; j0 += 8) {   // range lengths all %8 == 0
            float xv0 = px[(size_t)(b0 + xb) * D_ + j0 + xj];
            float xv1 = px[(size_t)(b0 + 32 + xb) * D_ + j0 + xj];
            float4 wv = make_float4(0, 0, 0, 0);
            if (t < 128) wv = *(const float4*)(W + (size_t)(h0 + wh) * D_ + j0 + wj);
            __syncthreads();
            xs[xj * 64 + xb]      = xv0;
            xs[xj * 64 + 32 + xb] = xv1;
            if (t < 128) {
                ws[(wj + 0) * 64 + wh] = wv.x * LOG2E;
                ws[(wj + 1) * 64 + wh] = wv.y * LOG2E;
                ws[(wj + 2) * 64 + wh] = wv.z * LOG2E;
                ws[(wj + 3) * 64 + wh] = wv.w * LOG2E;
            }
            __syncthreads();
#pragma unroll
            for (int jj = 0; jj < 8; ++jj) {
                float4 xq = *(float4*)&xs[jj * 64 + tb * 4];
                float4 wq = *(float4*)&ws[jj * 64 + th * 4];
                float xa[4] = {xq.x, xq.y, xq.z, xq.w};
                float wa[4] = {wq.x, wq.y, wq.z, wq.w};
#pragma unroll
                for (int bi = 0; bi < 4; ++bi)
#pragma unroll
                    for (int hh = 0; hh < 4; ++hh)
                        acc[bi][hh] = fmaf(xa[bi], wa[hh], acc[bi][hh]);
            }
        }
        float* dst = G + (size_t)r * BH_;
#pragma unroll
        for (int bi = 0; bi < 4; ++bi) {
            float4 o = make_float4(acc[bi][0], acc[bi][1], acc[bi][2], acc[bi][3]);
            *(float4*)(dst + (size_t)(b0 + tb * 4 + bi) * H_ + h0 + th * 4) = o;
        }
    }
}

// ---------- DPP reduce: both 32-lane halves simultaneously ----------
template <int CTRL>
__device__ __forceinline__ float dpp_add(float p) {
    int s = __builtin_amdgcn_update_dpp(0, __float_as_int(p), CTRL, 0xf, 0xf, true);
    return p + __int_as_float(s);
}
__device__ __forceinline__ float reduce_halves(float p) {
    p = dpp_add<0x111>(p);
    p = dpp_add<0x112>(p);
    p = dpp_add<0x114>(p);
    p = dpp_add<0x118>(p);
    p = dpp_add<0x142>(p);   // lane31 = sum(0..31), lane63 = sum(32..63)
    return p;
}

// 8 packed bf16 (uint4) -> 8 floats; high elements keep junk low-mantissa bits
__device__ __forceinline__ void cvt8(uint4 u, float4& a, float4& b) {
    a.x = __uint_as_float(u.x << 16);
    a.y = __uint_as_float(u.x);
    a.z = __uint_as_float(u.y << 16);
    a.w = __uint_as_float(u.y);
    b.x = __uint_as_float(u.z << 16);
    b.y = __uint_as_float(u.z);
    b.z = __uint_as_float(u.w << 16);
    b.w = __uint_as_float(u.w);
}

// ---------- main scan: block = (s, row-pair), 4 waves = 4 hb; in-block hb reduce ----------
__global__ __launch_bounds__(256, 8) void nade_main(
    const float* __restrict__ px,            // [B, D]
    const float* __restrict__ c,             // [H]
    const unsigned short* __restrict__ VWb,  // bf16 images
    const float* __restrict__ G,             // [5][B][H] (log2 domain)
    const float* __restrict__ bias,          // [D]
    float* __restrict__ out)                 // [B, D] — written directly
{
    __shared__ float4 red[2][4][2];          // [parity][wid][half] — 256 B

    const int lane = threadIdx.x & 63;
    const int wid  = threadIdx.x >> 6;       // = hb
    const int bid  = blockIdx.x;             // 0..3071
    const int s    = bid % 6;
    const int rp   = bid / 6;                // 0..511
    const int half = lane >> 5;
    const int row  = rp * 2 + half;
    const int hl   = lane & 31;
    const int h0   = wid * 256 + hl * 8;

    const int i0s = seg_bound(s), i1s = seg_bound(s + 1);

    // A (log2 domain) = c*log2e + sum_{r<s} G_r
    float A[8];
    {
        float4 c0 = *(const float4*)(c + h0);
        float4 c1 = *(const float4*)(c + h0 + 4);
        A[0] = c0.x * LOG2E; A[1] = c0.y * LOG2E; A[2] = c0.z * LOG2E; A[3] = c0.w * LOG2E;
        A[4] = c1.x * LOG2E; A[5] = c1.y * LOG2E; A[6] = c1.z * LOG2E; A[7] = c1.w * LOG2E;
        for (int r = 0; r < s; ++r) {
            const float* gp = G + (size_t)r * BH_ + (size_t)row * H_ + h0;
            float4 g0 = *(const float4*)(gp);
            float4 g1 = *(const float4*)(gp + 4);
            A[0] += g0.x; A[1] += g0.y; A[2] += g0.z; A[3] += g0.w;
            A[4] += g1.x; A[5] += g1.y; A[6] += g1.z; A[7] += g1.w;
        }
    }

    const float* xp = px + (size_t)row * D_;
    const uint4* vw = (const uint4*)VWb + ((size_t)i0s * 4 + wid) * 64 + hl;

    // one step (8 h): hw exp2, grouped rcp over 8 q's; clamp exp arg to 15
    auto step8 = [&A](const float4& v0, const float4& v1,
                      const float4& w0, const float4& w1, float xi) -> float {
        float va[8] = {v0.x, v0.y, v0.z, v0.w, v1.x, v1.y, v1.z, v1.w};
        float wa[8] = {w0.x, w0.y, w0.z, w0.w, w1.x, w1.y, w1.z, w1.w};
        float q[8];
#pragma unroll
        for (int k = 0; k < 8; ++k) {
            float e = __builtin_amdgcn_exp2f(fminf(15.f, -A[k]));
            q[k] = 1.f + e;
            A[k] = fmaf(wa[k], xi, A[k]);
        }
        float a01 = fmaf(va[0], q[1], va[1] * q[0]);
        float a23 = fmaf(va[2], q[3], va[3] * q[2]);
        float a45 = fmaf(va[4], q[5], va[5] * q[4]);
        float a67 = fmaf(va[6], q[7], va[7] * q[6]);
        float q01 = q[0] * q[1], q23 = q[2] * q[3];
        float q45 = q[4] * q[5], q67 = q[6] * q[7];
        float n0123 = fmaf(a01, q23, a23 * q01);
        float n4567 = fmaf(a45, q67, a67 * q45);
        float q0123 = q01 * q23, q4567 = q45 * q67;
        float r = __builtin_amdgcn_rcpf(q0123 * q4567);
        float n = fmaf(n0123, q4567, n4567 * q0123);
        return n * r;
    };

    // preload current raw quads + first x group
    uint4 uv = vw[0], uw = vw[32];
    vw += 256;
    float4 xq = *(const float4*)(xp + i0s);

    for (int ib = i0s; ib < i1s; ib += 4) {     // all segment lengths %4 == 0
        int xb = (ib + 4 < i1s) ? (ib + 4) : i0s;
        float4 xq_n = *(const float4*)(xp + xb);
        float xa[4] = {xq.x, xq.y, xq.z, xq.w};
        float pr[4];
#pragma unroll
        for (int j = 0; j < 4; ++j) {
            uint4 uvn = vw[0], uwn = vw[32];    // prefetch next step (images padded past 784)
            vw += 256;
            float4 v0, v1, w0, w1;
            cvt8(uv, v0, v1);
            cvt8(uw, w0, w1);
            float p = step8(v0, v1, w0, w1, xa[j]);
            pr[j] = reduce_halves(p);
            uv = uvn; uw = uwn;
        }
        const int par = (ib >> 2) & 1;
        if (hl == 31) red[par][wid][half] = make_float4(pr[0], pr[1], pr[2], pr[3]);
        __syncthreads();
        if (threadIdx.x < 2) {                  // thread t handles row rp*2+t
            float4 b4 = *(const float4*)(bias + ib);
            float4 p0 = red[par][0][threadIdx.x];
            float4 p1 = red[par][1][threadIdx.x];
            float4 p2 = red[par][2][threadIdx.x];
            float4 p3 = red[par][3][threadIdx.x];
            float4 o;
            o.x = b4.x + ((p0.x + p1.x) + (p2.x + p3.x));
            o.y = b4.y + ((p0.y + p1.y) + (p2.y + p3.y));
            o.z = b4.z + ((p0.z + p1.z) + (p2.z + p3.z));
            o.w = b4.w + ((p0.w + p1.w) + (p2.w + p3.w));
            *(float4*)(out + (size_t)(rp * 2 + threadIdx.x) * D_ + ib) = o;
        }
        xq = xq_n;
    }
}

extern "C" void kernel_launch(void* const* d_in, const int* in_sizes, int n_in,
                              void* d_out, int out_size, void* d_ws, size_t ws_size,
                              hipStream_t stream) {
    const float* px   = (const float*)d_in[0];  // [B, D]
    const float* W    = (const float*)d_in[1];  // [H, D]
    const float* c    = (const float*)d_in[2];  // [H]
    const float* V    = (const float*)d_in[3];  // [D, H]
    const float* bias = (const float*)d_in[4];  // [D]
    float* out = (float*)d_out;                 // [B, D]

    unsigned short* VWb = (unsigned short*)d_ws;              // 788*4*512 ushorts = 3.23 MB
    float* G    = (float*)((char*)d_ws + (size_t)788 * 4096); // [5][B][H]

    prep<<<dim3(2080), 256, 0, stream>>>(V, W, px, VWb, G);

    // 3072 blocks x 4 waves; block = (segment, row-pair), waves = 4 hb quarters
    nade_main<<<dim3(3072), 256, 0, stream>>>(px, c, VWb, G, bias, out);
}